// Round 5
// baseline (107.692 us; speedup 1.0000x reference)
//
#include <hip/hip_runtime.h>

#define NROWS 32768
#define DDIM 1024
#define ROWS_PER_BLOCK 16   // 4 waves/block x 4 row-groups/wave

using f32x4 = __attribute__((ext_vector_type(4))) float;

static __device__ __forceinline__ float dot4(f32x4 a, f32x4 b) {
    return a.x * b.x + a.y * b.y + a.z * b.z + a.w * b.w;
}

__global__ __launch_bounds__(256) void cosloss_main(const float* __restrict__ pred,
                                                    const float* __restrict__ gt,
                                                    float* __restrict__ partial) {
    const int wave = threadIdx.x >> 6;
    const int lane = threadIdx.x & 63;
    const int grp  = lane >> 4;      // 4 groups of 16 lanes; one row each
    const int sub  = lane & 15;
    __shared__ float s_wave[4];

    const int row = blockIdx.x * ROWS_PER_BLOCK + wave * 4 + grp;
    const f32x4* pp = (const f32x4*)(pred + (size_t)row * (2 * DDIM));
    const f32x4* gg = (const f32x4*)(gt + (size_t)row * (2 * DDIM));

    float np0 = 0.f, np1 = 0.f, ng0 = 0.f, ng1 = 0.f;
    float d00 = 0.f, d01 = 0.f, d10 = 0.f, d11 = 0.f;

    // depth-2 software pipeline over 16 iterations (256 float4s/slot, 16 lanes/row)
    // plain loads (no nontemporal hint): data has zero intra-dispatch reuse but
    // the 256 MiB L3 retains ~half the 512 MB working set across replays —
    // don't suppress that retention.
    f32x4 a0 = pp[sub];
    f32x4 a1 = pp[sub + 256];
    f32x4 b0 = gg[sub];
    f32x4 b1 = gg[sub + 256];

    #pragma unroll 5
    for (int i = 0; i < 15; ++i) {
        const int idx = (i + 1) * 16 + sub;
        f32x4 na0 = pp[idx];
        f32x4 na1 = pp[idx + 256];
        f32x4 nb0 = gg[idx];
        f32x4 nb1 = gg[idx + 256];
        np0 += dot4(a0, a0);
        np1 += dot4(a1, a1);
        ng0 += dot4(b0, b0);
        ng1 += dot4(b1, b1);
        d00 += dot4(a0, b0);
        d01 += dot4(a0, b1);
        d10 += dot4(a1, b0);
        d11 += dot4(a1, b1);
        a0 = na0; a1 = na1; b0 = nb0; b1 = nb1;
    }
    np0 += dot4(a0, a0);
    np1 += dot4(a1, a1);
    ng0 += dot4(b0, b0);
    ng1 += dot4(b1, b1);
    d00 += dot4(a0, b0);
    d01 += dot4(a0, b1);
    d10 += dot4(a1, b0);
    d11 += dot4(a1, b1);

    // butterfly reduce within each 16-lane group (offsets 1,2,4,8)
    #pragma unroll
    for (int off = 1; off < 16; off <<= 1) {
        np0 += __shfl_xor(np0, off);
        np1 += __shfl_xor(np1, off);
        ng0 += __shfl_xor(ng0, off);
        ng1 += __shfl_xor(ng1, off);
        d00 += __shfl_xor(d00, off);
        d01 += __shfl_xor(d01, off);
        d10 += __shfl_xor(d10, off);
        d11 += __shfl_xor(d11, off);
    }

    float best = 0.0f;
    if (sub == 0) {
        const float EPS = 1e-12f;
        float ip0 = 1.0f / fmaxf(sqrtf(np0), EPS);
        float ip1 = 1.0f / fmaxf(sqrtf(np1), EPS);
        float ig0 = 1.0f / fmaxf(sqrtf(ng0), EPS);
        float ig1 = 1.0f / fmaxf(sqrtf(ng1), EPS);
        float c00 = d00 * ip0 * ig0;
        float c01 = d01 * ip0 * ig1;
        float c10 = d10 * ip1 * ig0;
        float c11 = d11 * ip1 * ig1;
        float s_id = c00 + c11;
        float s_sw = c01 + c10;
        best = (s_id >= s_sw) ? s_id : s_sw;
    }
    // combine the 4 groups' lane-0 contributions across the wave
    best += __shfl_xor(best, 16);
    best += __shfl_xor(best, 32);

    if (lane == 0) s_wave[wave] = best;
    __syncthreads();
    if (threadIdx.x == 0) {
        partial[blockIdx.x] = s_wave[0] + s_wave[1] + s_wave[2] + s_wave[3];
    }
}

__global__ __launch_bounds__(256) void cosloss_final(const float* __restrict__ partial,
                                                     float* __restrict__ out, int n) {
    __shared__ float s[256];
    float acc = 0.0f;
    for (int i = threadIdx.x; i < n; i += 256) acc += partial[i];
    s[threadIdx.x] = acc;
    __syncthreads();
    for (int step = 128; step; step >>= 1) {
        if (threadIdx.x < step) s[threadIdx.x] += s[threadIdx.x + step];
        __syncthreads();
    }
    if (threadIdx.x == 0) out[0] = 1.0f - s[0] / (2.0f * (float)NROWS);
}

extern "C" void kernel_launch(void* const* d_in, const int* in_sizes, int n_in,
                              void* d_out, int out_size, void* d_ws, size_t ws_size,
                              hipStream_t stream) {
    const float* pred = (const float*)d_in[0];
    const float* gt   = (const float*)d_in[1];
    float* out        = (float*)d_out;
    float* partial    = (float*)d_ws;   // 2048 floats = 8 KB

    const int nblocks = NROWS / ROWS_PER_BLOCK;  // 2048
    cosloss_main<<<nblocks, 256, 0, stream>>>(pred, gt, partial);
    cosloss_final<<<1, 256, 0, stream>>>(partial, out, nblocks);
}

// Round 6
// 102.632 us; speedup vs baseline: 1.0493x; 1.0493x over previous
//
#include <hip/hip_runtime.h>

#define NROWS 32768
#define DDIM 1024
#define ROWS_PER_BLOCK 16   // 4 waves/block x 4 row-groups/wave
#define NBLOCKS (NROWS / ROWS_PER_BLOCK)   // 2048

using f32x4 = __attribute__((ext_vector_type(4))) float;

static __device__ __forceinline__ float dot4(f32x4 a, f32x4 b) {
    return a.x * b.x + a.y * b.y + a.z * b.z + a.w * b.w;
}

static __device__ __forceinline__ f32x4 ntload(const f32x4* p) {
    return __builtin_nontemporal_load(p);   // R5 A/B: nt is +17% on this stream
}

__global__ __launch_bounds__(256) void cosloss_main(const float* __restrict__ pred,
                                                    const float* __restrict__ gt,
                                                    float* __restrict__ out) {
    const int wave = threadIdx.x >> 6;
    const int lane = threadIdx.x & 63;
    const int grp  = lane >> 4;      // 4 groups of 16 lanes; one row each
    const int sub  = lane & 15;
    __shared__ float s_wave[4];

    const int row = blockIdx.x * ROWS_PER_BLOCK + wave * 4 + grp;
    const f32x4* pp = (const f32x4*)(pred + (size_t)row * (2 * DDIM));
    const f32x4* gg = (const f32x4*)(gt + (size_t)row * (2 * DDIM));

    float np0 = 0.f, np1 = 0.f, ng0 = 0.f, ng1 = 0.f;
    float d00 = 0.f, d01 = 0.f, d10 = 0.f, d11 = 0.f;

    // depth-2 software pipeline over 16 iterations (256 float4s/slot, 16 lanes/row)
    f32x4 a0 = ntload(pp + sub);
    f32x4 a1 = ntload(pp + sub + 256);
    f32x4 b0 = ntload(gg + sub);
    f32x4 b1 = ntload(gg + sub + 256);

    #pragma unroll 5
    for (int i = 0; i < 15; ++i) {
        const int idx = (i + 1) * 16 + sub;
        f32x4 na0 = ntload(pp + idx);
        f32x4 na1 = ntload(pp + idx + 256);
        f32x4 nb0 = ntload(gg + idx);
        f32x4 nb1 = ntload(gg + idx + 256);
        np0 += dot4(a0, a0);
        np1 += dot4(a1, a1);
        ng0 += dot4(b0, b0);
        ng1 += dot4(b1, b1);
        d00 += dot4(a0, b0);
        d01 += dot4(a0, b1);
        d10 += dot4(a1, b0);
        d11 += dot4(a1, b1);
        a0 = na0; a1 = na1; b0 = nb0; b1 = nb1;
    }
    np0 += dot4(a0, a0);
    np1 += dot4(a1, a1);
    ng0 += dot4(b0, b0);
    ng1 += dot4(b1, b1);
    d00 += dot4(a0, b0);
    d01 += dot4(a0, b1);
    d10 += dot4(a1, b0);
    d11 += dot4(a1, b1);

    // butterfly reduce within each 16-lane group (offsets 1,2,4,8)
    #pragma unroll
    for (int off = 1; off < 16; off <<= 1) {
        np0 += __shfl_xor(np0, off);
        np1 += __shfl_xor(np1, off);
        ng0 += __shfl_xor(ng0, off);
        ng1 += __shfl_xor(ng1, off);
        d00 += __shfl_xor(d00, off);
        d01 += __shfl_xor(d01, off);
        d10 += __shfl_xor(d10, off);
        d11 += __shfl_xor(d11, off);
    }

    float best = 0.0f;
    if (sub == 0) {
        const float EPS = 1e-12f;
        float ip0 = 1.0f / fmaxf(sqrtf(np0), EPS);
        float ip1 = 1.0f / fmaxf(sqrtf(np1), EPS);
        float ig0 = 1.0f / fmaxf(sqrtf(ng0), EPS);
        float ig1 = 1.0f / fmaxf(sqrtf(ng1), EPS);
        float c00 = d00 * ip0 * ig0;
        float c01 = d01 * ip0 * ig1;
        float c10 = d10 * ip1 * ig0;
        float c11 = d11 * ip1 * ig1;
        float s_id = c00 + c11;
        float s_sw = c01 + c10;
        best = (s_id >= s_sw) ? s_id : s_sw;
    }
    // combine the 4 groups' lane-0 contributions across the wave
    best += __shfl_xor(best, 16);
    best += __shfl_xor(best, 32);

    if (lane == 0) s_wave[wave] = best;
    __syncthreads();
    if (threadIdx.x == 0) {
        float blocksum = s_wave[0] + s_wave[1] + s_wave[2] + s_wave[3];
        // loss = sum over blocks of (ROWS_PER_BLOCK - blocksum/2) / NROWS.
        // One relaxed HW fp32 atomic per block (no fences -> no L2 writeback
        // storm, unlike R3's acq/rel ticket). out[] is memset to 0 per call.
        float contrib = ((float)ROWS_PER_BLOCK - 0.5f * blocksum) / (float)NROWS;
        unsafeAtomicAdd(out, contrib);
    }
}

extern "C" void kernel_launch(void* const* d_in, const int* in_sizes, int n_in,
                              void* d_out, int out_size, void* d_ws, size_t ws_size,
                              hipStream_t stream) {
    const float* pred = (const float*)d_in[0];
    const float* gt   = (const float*)d_in[1];
    float* out        = (float*)d_out;

    hipMemsetAsync(out, 0, sizeof(float), stream);   // accumulator starts at 0
    cosloss_main<<<NBLOCKS, 256, 0, stream>>>(pred, gt, out);
}

// Round 7
// 87.817 us; speedup vs baseline: 1.2263x; 1.1687x over previous
//
#include <hip/hip_runtime.h>

#define NROWS 32768
#define DDIM 1024
#define ROWS_PER_BLOCK 16   // 4 waves/block x 4 row-groups/wave

using f32x4 = __attribute__((ext_vector_type(4))) float;

static __device__ __forceinline__ float dot4(f32x4 a, f32x4 b) {
    return a.x * b.x + a.y * b.y + a.z * b.z + a.w * b.w;
}

static __device__ __forceinline__ f32x4 ntload(const f32x4* p) {
    return __builtin_nontemporal_load(p);   // R5 A/B: nt is +17% on this stream
}

__global__ __launch_bounds__(256) void cosloss_main(const float* __restrict__ pred,
                                                    const float* __restrict__ gt,
                                                    float* __restrict__ partial) {
    const int wave = threadIdx.x >> 6;
    const int lane = threadIdx.x & 63;
    const int grp  = lane >> 4;      // 4 groups of 16 lanes; one row each
    const int sub  = lane & 15;
    __shared__ float s_wave[4];

    const int row = blockIdx.x * ROWS_PER_BLOCK + wave * 4 + grp;
    const f32x4* pp = (const f32x4*)(pred + (size_t)row * (2 * DDIM));
    const f32x4* gg = (const f32x4*)(gt + (size_t)row * (2 * DDIM));

    float np0 = 0.f, np1 = 0.f, ng0 = 0.f, ng1 = 0.f;
    float d00 = 0.f, d01 = 0.f, d10 = 0.f, d11 = 0.f;

    // depth-2 software pipeline over 16 iterations (256 float4s/slot, 16 lanes/row)
    f32x4 a0 = ntload(pp + sub);
    f32x4 a1 = ntload(pp + sub + 256);
    f32x4 b0 = ntload(gg + sub);
    f32x4 b1 = ntload(gg + sub + 256);

    #pragma unroll 5
    for (int i = 0; i < 15; ++i) {
        const int idx = (i + 1) * 16 + sub;
        f32x4 na0 = ntload(pp + idx);
        f32x4 na1 = ntload(pp + idx + 256);
        f32x4 nb0 = ntload(gg + idx);
        f32x4 nb1 = ntload(gg + idx + 256);
        np0 += dot4(a0, a0);
        np1 += dot4(a1, a1);
        ng0 += dot4(b0, b0);
        ng1 += dot4(b1, b1);
        d00 += dot4(a0, b0);
        d01 += dot4(a0, b1);
        d10 += dot4(a1, b0);
        d11 += dot4(a1, b1);
        a0 = na0; a1 = na1; b0 = nb0; b1 = nb1;
    }
    np0 += dot4(a0, a0);
    np1 += dot4(a1, a1);
    ng0 += dot4(b0, b0);
    ng1 += dot4(b1, b1);
    d00 += dot4(a0, b0);
    d01 += dot4(a0, b1);
    d10 += dot4(a1, b0);
    d11 += dot4(a1, b1);

    // butterfly reduce within each 16-lane group (offsets 1,2,4,8)
    #pragma unroll
    for (int off = 1; off < 16; off <<= 1) {
        np0 += __shfl_xor(np0, off);
        np1 += __shfl_xor(np1, off);
        ng0 += __shfl_xor(ng0, off);
        ng1 += __shfl_xor(ng1, off);
        d00 += __shfl_xor(d00, off);
        d01 += __shfl_xor(d01, off);
        d10 += __shfl_xor(d10, off);
        d11 += __shfl_xor(d11, off);
    }

    float best = 0.0f;
    if (sub == 0) {
        const float EPS = 1e-12f;
        float ip0 = 1.0f / fmaxf(sqrtf(np0), EPS);
        float ip1 = 1.0f / fmaxf(sqrtf(np1), EPS);
        float ig0 = 1.0f / fmaxf(sqrtf(ng0), EPS);
        float ig1 = 1.0f / fmaxf(sqrtf(ng1), EPS);
        float c00 = d00 * ip0 * ig0;
        float c01 = d01 * ip0 * ig1;
        float c10 = d10 * ip1 * ig0;
        float c11 = d11 * ip1 * ig1;
        float s_id = c00 + c11;
        float s_sw = c01 + c10;
        best = (s_id >= s_sw) ? s_id : s_sw;
    }
    // combine the 4 groups' lane-0 contributions across the wave
    best += __shfl_xor(best, 16);
    best += __shfl_xor(best, 32);

    if (lane == 0) s_wave[wave] = best;
    __syncthreads();
    if (threadIdx.x == 0) {
        partial[blockIdx.x] = s_wave[0] + s_wave[1] + s_wave[2] + s_wave[3];
    }
}

__global__ __launch_bounds__(256) void cosloss_final(const float* __restrict__ partial,
                                                     float* __restrict__ out, int n) {
    __shared__ float s[256];
    float acc = 0.0f;
    for (int i = threadIdx.x; i < n; i += 256) acc += partial[i];
    s[threadIdx.x] = acc;
    __syncthreads();
    for (int step = 128; step; step >>= 1) {
        if (threadIdx.x < step) s[threadIdx.x] += s[threadIdx.x + step];
        __syncthreads();
    }
    if (threadIdx.x == 0) out[0] = 1.0f - s[0] / (2.0f * (float)NROWS);
}

extern "C" void kernel_launch(void* const* d_in, const int* in_sizes, int n_in,
                              void* d_out, int out_size, void* d_ws, size_t ws_size,
                              hipStream_t stream) {
    const float* pred = (const float*)d_in[0];
    const float* gt   = (const float*)d_in[1];
    float* out        = (float*)d_out;
    float* partial    = (float*)d_ws;   // 2048 floats = 8 KB

    const int nblocks = NROWS / ROWS_PER_BLOCK;  // 2048
    cosloss_main<<<nblocks, 256, 0, stream>>>(pred, gt, partial);
    cosloss_final<<<1, 256, 0, stream>>>(partial, out, nblocks);
}